// Round 17
// baseline (597.455 us; speedup 1.0000x reference)
//
#include <hip/hip_runtime.h>
#include <hip/hip_bf16.h>
#include <math.h>

// Problem constants
#define B_   8
#define H_   128
#define W_   128
#define C_   256
#define WS_  8
#define SS_  4
#define NH_  8
#define HD_  32
#define MROWS 131072   // B * H * W tokens

typedef short bf16x8 __attribute__((ext_vector_type(8)));
typedef float f32x4  __attribute__((ext_vector_type(4)));

__device__ __forceinline__ unsigned short f2bf(float f) {
    unsigned int u = __float_as_uint(f);
    u += 0x7fffu + ((u >> 16) & 1u);          // round-to-nearest-even
    return (unsigned short)(u >> 16);
}
__device__ __forceinline__ float bfl(unsigned int u) {   // low bf16 of u -> f32
    return __uint_as_float(u << 16);
}
__device__ __forceinline__ float bfh(unsigned int u) {   // high bf16 of u -> f32
    return __uint_as_float(u & 0xffff0000u);
}

// packed f32x2 -> bf16x2 (compiler emits v_cvt_pk_bf16_f32)
__device__ __forceinline__ unsigned int pk2(float a, float b) {
    __hip_bfloat162 h = __float22bfloat162_rn(make_float2(a, b));
    unsigned int u;
    __builtin_memcpy(&u, &h, 4);
    return u;
}

// async global->LDS, 16 bytes per lane; lds dest = wave-uniform base + lane*16
__device__ __forceinline__ void gload16(const unsigned short* g, unsigned short* l) {
    __builtin_amdgcn_global_load_lds(
        (const __attribute__((address_space(1))) unsigned int*)(const void*)g,
        (__attribute__((address_space(3))) unsigned int*)(void*)l, 16, 0, 0);
}

// cheap GELU: v * sigmoid(1.702 v)  (max |err| ~0.02, inside bf16-grade budget)
__device__ __forceinline__ float fast_gelu2(float v) {
    return v * __builtin_amdgcn_rcpf(1.0f + __expf(-1.702f * v));
}

// ---------------------------------------------------------------------------
// fp32 -> bf16 weight conversion
// ---------------------------------------------------------------------------
__global__ __launch_bounds__(256) void cvt4(const float* __restrict__ s,
                                            unsigned short* __restrict__ d, int n) {
    const int i = (blockIdx.x * 256 + threadIdx.x) * 4;
    if (i >= n) return;
    const float4 v = *(const float4*)(s + i);
    ushort4 o;
    o.x = f2bf(v.x); o.y = f2bf(v.y); o.z = f2bf(v.z); o.w = f2bf(v.w);
    *(ushort4*)(d + i) = o;
}

// ---------------------------------------------------------------------------
// FUSED LN1 + QKV GEMM (R15 — passing). 256 thr, block = 128 rows, 4 waves.
// ---------------------------------------------------------------------------
template<int N>
__global__ __launch_bounds__(256, 2) void ln1_qkv(const float* __restrict__ x,
                                                  const float* __restrict__ g1,
                                                  const float* __restrict__ b1n,
                                                  const unsigned short* __restrict__ W,
                                                  const float* __restrict__ bias,
                                                  unsigned short* __restrict__ Cout) {
    __shared__ unsigned short W_lds[2][64 * 256];

    const int t    = threadIdx.x;
    const int wave = t >> 6, lane = t & 63;
    const int fr   = lane & 15, h = lane >> 4;
    const int m0   = blockIdx.x * 128;
    constexpr int NT = N / 64;

    auto stage = [&](int b, int nt) {
        const unsigned short* Wt = W + (size_t)nt * 64 * 256;
#pragma unroll
        for (int q = 0; q < 8; ++q) {
            const int d    = q * 4096 + t * 16;            // dest byte offset
            const int row  = d >> 9;
            const int colb = (d & 511) ^ ((row & 7) << 4); // swizzled source col
            gload16(Wt + (size_t)row * 256 + (colb >> 1),
                    &W_lds[b][(q * 4096 + wave * 1024) >> 1]);
        }
    };

    stage(0, 0);                 // overlaps with the LN compute below

    // --- fused LN1 + shift-gather into A fragments
    bf16x8 aw[2][8];
#pragma unroll
    for (int mi = 0; mi < 2; ++mi) {
        const int m    = m0 + wave * 32 + mi * 16 + fr;
        const int bimg = m >> 14;
        const int rem  = m & 16383;
        const int win  = rem >> 6;
        const int tok  = rem & 63;
        const int hp = (win >> 4) * 8 + (tok >> 3);
        const int wp = (win & 15) * 8 + (tok & 7);
        const int ho = (hp + SS_) & (H_ - 1);
        const int wo = (wp + SS_) & (W_ - 1);
        const float* xr = x + ((size_t)(bimg << 14) + ho * W_ + wo) * C_;

        float4 va[8], vb[8];
        float s = 0.0f, ss = 0.0f;
#pragma unroll
        for (int ks = 0; ks < 8; ++ks) {
            va[ks] = *(const float4*)&xr[ks * 32 + h * 8];
            vb[ks] = *(const float4*)&xr[ks * 32 + h * 8 + 4];
            s  += va[ks].x + va[ks].y + va[ks].z + va[ks].w
                + vb[ks].x + vb[ks].y + vb[ks].z + vb[ks].w;
            ss += va[ks].x*va[ks].x + va[ks].y*va[ks].y + va[ks].z*va[ks].z + va[ks].w*va[ks].w
                + vb[ks].x*vb[ks].x + vb[ks].y*vb[ks].y + vb[ks].z*vb[ks].z + vb[ks].w*vb[ks].w;
        }
        s  += __shfl_xor(s, 16, 64);  s  += __shfl_xor(s, 32, 64);
        ss += __shfl_xor(ss, 16, 64); ss += __shfl_xor(ss, 32, 64);
        const float mean = s * (1.0f / 256.0f);
        const float rstd = rsqrtf(ss * (1.0f / 256.0f) - mean * mean + 1e-5f);

#pragma unroll
        for (int ks = 0; ks < 8; ++ks) {
            const float4 g0 = *(const float4*)&g1 [ks * 32 + h * 8];
            const float4 g4 = *(const float4*)&g1 [ks * 32 + h * 8 + 4];
            const float4 c0 = *(const float4*)&b1n[ks * 32 + h * 8];
            const float4 c4 = *(const float4*)&b1n[ks * 32 + h * 8 + 4];
            uint4 u;
            u.x = pk2((va[ks].x - mean) * rstd * g0.x + c0.x,
                      (va[ks].y - mean) * rstd * g0.y + c0.y);
            u.y = pk2((va[ks].z - mean) * rstd * g0.z + c0.z,
                      (va[ks].w - mean) * rstd * g0.w + c0.w);
            u.z = pk2((vb[ks].x - mean) * rstd * g4.x + c4.x,
                      (vb[ks].y - mean) * rstd * g4.y + c4.y);
            u.w = pk2((vb[ks].z - mean) * rstd * g4.z + c4.z,
                      (vb[ks].w - mean) * rstd * g4.w + c4.w);
            aw[mi][ks] = *(bf16x8*)&u;
        }
    }

    __syncthreads();             // W tile 0 landed

    for (int nt = 0; nt < NT; ++nt) {
        if (nt + 1 < NT) stage((nt + 1) & 1, nt + 1);

        const char* buf = (const char*)W_lds[nt & 1];
        f32x4 acc[2][4] = {};
#pragma unroll
        for (int nj = 0; nj < 4; ++nj) {
            const int   wrow = nj * 16 + fr;
            const char* wb   = buf + wrow * 512;
            const int   swz  = (fr & 7) << 4;
            bf16x8 wf[8];
#pragma unroll
            for (int ks = 0; ks < 8; ++ks)
                wf[ks] = *(const bf16x8*)(wb + ((ks * 64 + h * 16) ^ swz));
#pragma unroll
            for (int ks = 0; ks < 8; ++ks) {
                acc[0][nj] = __builtin_amdgcn_mfma_f32_16x16x32_bf16(wf[ks], aw[0][ks], acc[0][nj], 0, 0, 0);
                acc[1][nj] = __builtin_amdgcn_mfma_f32_16x16x32_bf16(wf[ks], aw[1][ks], acc[1][nj], 0, 0, 0);
            }
        }

#pragma unroll
        for (int nj = 0; nj < 4; ++nj) {
            const int n = nt * 64 + nj * 16 + h * 4;
            const float4 bb = *(const float4*)&bias[n];
#pragma unroll
            for (int mi = 0; mi < 2; ++mi) {
                const int m = m0 + wave * 32 + mi * 16 + fr;
                uint2 pk;
                pk.x = pk2(acc[mi][nj][0] + bb.x, acc[mi][nj][1] + bb.y);
                pk.y = pk2(acc[mi][nj][2] + bb.z, acc[mi][nj][3] + bb.w);
                *(uint2*)&Cout[(size_t)m * N + n] = pk;
            }
        }
        __syncthreads();
    }
}

// ---------------------------------------------------------------------------
// Fused MLP v5: out = bf16(x1) + gelu(ln2out @ W1^T + b1) @ W2^T + b2.
// R17: 1024 thr / 16 waves, block = 256 rows. Halved per-wave tiles:
//   FC1: 16 rows/wave (aw[8] = 32 VGPR); FC2: 4x4 wave grid, 64x64 tile
//   (acc2[4][4] = 64 VGPR). Persistent regs 96 -> fits the 128-VGPR cap a
//   1024-thr block requires -> 16 waves/CU (2x R16's 8). Schedule = R13.
// LDS 96 KB (W1/W2/G all double-buffered), 1 block/CU.
// ---------------------------------------------------------------------------
__global__ __launch_bounds__(1024) void mlp_fused(const unsigned short* __restrict__ A,
                                                  const unsigned short* __restrict__ W1,
                                                  const float* __restrict__ b1,
                                                  const unsigned short* __restrict__ W2,
                                                  const float* __restrict__ b2,
                                                  const unsigned short* __restrict__ x1b,
                                                  float* __restrict__ out) {
    __shared__ unsigned short W1_lds[2][32 * 256];   // 2 x 16 KB
    __shared__ unsigned short W2_lds[2][256 * 32];   // 2 x 16 KB
    __shared__ unsigned short G_lds [2][256 * 32];   // 2 x 16 KB

    const int t    = threadIdx.x;
    const int wave = t >> 6, lane = t & 63;
    const int fr   = lane & 15, h = lane >> 4;
    const int wr   = wave >> 2, wc = wave & 3;       // FC2 wave grid 4x4
    const int m0   = blockIdx.x * 256;
    constexpr int NC = 32;                           // 32 chunks x 32 cols = 1024

    // FC1 A fragments: wave owns rows [wave*16, wave*16+16), full K=256
    bf16x8 aw[8];
    const unsigned short* Abase = A + (size_t)(m0 + wave * 16 + fr) * 256 + h * 8;
#pragma unroll
    for (int ks = 0; ks < 8; ++ks)
        aw[ks] = *(const bf16x8*)(Abase + ks * 32);

    auto stageW1 = [&](int b, int c) {               // 32 rows x 512 B = 16 KB
        const unsigned short* Wt = W1 + (size_t)c * 32 * 256;
        const int d    = t * 16;
        const int row  = d >> 9;
        const int colb = (d & 511) ^ ((row & 7) << 4);
        gload16(Wt + (size_t)row * 256 + (colb >> 1),
                &W1_lds[b][(wave * 1024) >> 1]);
    };
    auto stageW2 = [&](int b, int c) {               // 256 rows x 64 B = 16 KB
        const int d    = t * 16;
        const int row  = d >> 6;
        const int colb = (d & 63) ^ ((row & 3) << 4);
        gload16(W2 + (size_t)row * 1024 + c * 32 + (colb >> 1),
                &W2_lds[b][(wave * 1024) >> 1]);
    };

    auto fc1 = [&](int cc, int gb) {
        const char* buf = (const char*)W1_lds[cc & 1];
        const int   swz = (fr & 7) << 4;
#pragma unroll
        for (int nj = 0; nj < 2; ++nj) {
            const int   wrow = nj * 16 + fr;
            const char* wb   = buf + wrow * 512;
            f32x4 g0 = {};
#pragma unroll
            for (int kh = 0; kh < 2; ++kh) {         // wf in halves: fewer live regs
                bf16x8 wf[4];
#pragma unroll
                for (int ks = 0; ks < 4; ++ks)
                    wf[ks] = *(const bf16x8*)(wb + (((kh * 4 + ks) * 64 + h * 16) ^ swz));
#pragma unroll
                for (int ks = 0; ks < 4; ++ks)
                    g0 = __builtin_amdgcn_mfma_f32_16x16x32_bf16(wf[ks], aw[kh * 4 + ks], g0, 0, 0, 0);
            }
            const float4 bb = *(const float4*)&b1[cc * 32 + nj * 16 + h * 4];
            const int row = wave * 16 + fr;
            const int off = (nj * 32 + h * 8) ^ ((row & 3) << 4);
            uint2 pk;
            pk.x = pk2(fast_gelu2(g0[0] + bb.x), fast_gelu2(g0[1] + bb.y));
            pk.y = pk2(fast_gelu2(g0[2] + bb.z), fast_gelu2(g0[3] + bb.w));
            *(uint2*)((char*)G_lds[gb] + row * 64 + off) = pk;
        }
    };

    f32x4 acc2[4][4] = {};

    // prologue
    stageW1(0, 0);
    stageW2(0, 0);
    asm volatile("s_waitcnt vmcnt(0)" ::: "memory");
    __builtin_amdgcn_sched_barrier(0);
    __builtin_amdgcn_s_barrier();
    stageW1(1, 1);
    fc1(0, 0);

    for (int c = 0; c < NC; ++c) {
        asm volatile("s_waitcnt vmcnt(0) lgkmcnt(0)" ::: "memory");
        __builtin_amdgcn_sched_barrier(0);
        __builtin_amdgcn_s_barrier();

        if (c + 2 < NC) stageW1(c & 1, c + 2);
        if (c + 1 < NC) stageW2((c + 1) & 1, c + 1);

        // ---- FC2(c): acc2 += G[c&1] @ W2[c&1]^T  (K-chunk = 32)
        {
            const char* Gb = (const char*)G_lds[c & 1];
            const char* Wb = (const char*)W2_lds[c & 1];
            bf16x8 w2f[4];
#pragma unroll
            for (int nj2 = 0; nj2 < 4; ++nj2) {
                const int wrow2 = wc * 64 + nj2 * 16 + fr;
                w2f[nj2] = *(const bf16x8*)(Wb + wrow2 * 64 + ((h * 16) ^ ((wrow2 & 3) << 4)));
            }
#pragma unroll
            for (int mi2 = 0; mi2 < 4; ++mi2) {
                const int grow = wr * 64 + mi2 * 16 + fr;
                const bf16x8 gf = *(const bf16x8*)(Gb + grow * 64 + ((h * 16) ^ ((grow & 3) << 4)));
#pragma unroll
                for (int nj2 = 0; nj2 < 4; ++nj2)
                    acc2[mi2][nj2] = __builtin_amdgcn_mfma_f32_16x16x32_bf16(
                        w2f[nj2], gf, acc2[mi2][nj2], 0, 0, 0);
            }
        }

        if (c + 1 < NC) fc1(c + 1, (c + 1) & 1);
    }

    // epilogue: out[m][n] = bf16resid(x1b) + acc2 + b2  (full overwrite)
    float4 bv[4];
#pragma unroll
    for (int nj2 = 0; nj2 < 4; ++nj2)
        bv[nj2] = *(const float4*)&b2[wc * 64 + nj2 * 16 + h * 4];

#pragma unroll
    for (int mi2 = 0; mi2 < 4; ++mi2) {
        const int m = m0 + wr * 64 + mi2 * 16 + fr;
#pragma unroll
        for (int nj2 = 0; nj2 < 4; ++nj2) {
            const int n = wc * 64 + nj2 * 16 + h * 4;
            const size_t idx = (size_t)m * 256 + n;
            const uint2 rb = *(const uint2*)&x1b[idx];
            float4 o;
            o.x = acc2[mi2][nj2][0] + bv[nj2].x + bfl(rb.x);
            o.y = acc2[mi2][nj2][1] + bv[nj2].y + bfh(rb.x);
            o.z = acc2[mi2][nj2][2] + bv[nj2].z + bfl(rb.y);
            o.w = acc2[mi2][nj2][3] + bv[nj2].w + bfh(rb.y);
            *(float4*)&out[idx] = o;
        }
    }
}

// ---------------------------------------------------------------------------
// proj GEMM (K=256, N=256) + window-reverse/unshift scatter + residual +
// FUSED LayerNorm2. x1 stored as BF16 (x1b) — no fp32 out write.
// ---------------------------------------------------------------------------
__global__ __launch_bounds__(256, 2) void proj_ln2(const unsigned short* __restrict__ A,
                                                   const unsigned short* __restrict__ W,
                                                   const float* __restrict__ bias,
                                                   const float* __restrict__ resid,
                                                   const float* __restrict__ g2,
                                                   const float* __restrict__ b2,
                                                   unsigned short* __restrict__ x1b,
                                                   unsigned short* __restrict__ ln2out) {
    __shared__ unsigned short W_lds[2][64 * 256];

    const int t    = threadIdx.x;
    const int wave = t >> 6, lane = t & 63;
    const int fr   = lane & 15, h = lane >> 4;
    const int m0   = blockIdx.x * 128;

    bf16x8 aw[2][8];
    const unsigned short* Abase = A + (size_t)(m0 + wave * 32 + fr) * 256 + h * 8;
#pragma unroll
    for (int mi = 0; mi < 2; ++mi)
#pragma unroll
        for (int ks = 0; ks < 8; ++ks)
            aw[mi][ks] = *(const bf16x8*)(Abase + mi * 16 * 256 + ks * 32);

    auto stage = [&](int b, int nt) {
        const unsigned short* Wt = W + (size_t)nt * 64 * 256;
#pragma unroll
        for (int q = 0; q < 8; ++q) {
            const int d    = q * 4096 + t * 16;
            const int row  = d >> 9;
            const int colb = (d & 511) ^ ((row & 7) << 4);
            gload16(Wt + (size_t)row * 256 + (colb >> 1),
                    &W_lds[b][(q * 4096 + wave * 1024) >> 1]);
        }
    };

    stage(0, 0);
    __syncthreads();

    f32x4 acc[2][16] = {};
    for (int nt = 0; nt < 4; ++nt) {
        if (nt < 3) stage((nt + 1) & 1, nt + 1);
        const char* buf = (const char*)W_lds[nt & 1];
#pragma unroll
        for (int nj = 0; nj < 4; ++nj) {
            const int   wrow = nj * 16 + fr;
            const char* wb   = buf + wrow * 512;
            const int   swz  = (fr & 7) << 4;
            bf16x8 wf[8];
#pragma unroll
            for (int ks = 0; ks < 8; ++ks)
                wf[ks] = *(const bf16x8*)(wb + ((ks * 64 + h * 16) ^ swz));
            switch (nt) {
            case 0:
#pragma unroll
                for (int ks = 0; ks < 8; ++ks) {
                    acc[0][0 + nj] = __builtin_amdgcn_mfma_f32_16x16x32_bf16(wf[ks], aw[0][ks], acc[0][0 + nj], 0, 0, 0);
                    acc[1][0 + nj] = __builtin_amdgcn_mfma_f32_16x16x32_bf16(wf[ks], aw[1][ks], acc[1][0 + nj], 0, 0, 0);
                } break;
            case 1:
#pragma unroll
                for (int ks = 0; ks < 8; ++ks) {
                    acc[0][4 + nj] = __builtin_amdgcn_mfma_f32_16x16x32_bf16(wf[ks], aw[0][ks], acc[0][4 + nj], 0, 0, 0);
                    acc[1][4 + nj] = __builtin_amdgcn_mfma_f32_16x16x32_bf16(wf[ks], aw[1][ks], acc[1][4 + nj], 0, 0, 0);
                } break;
            case 2:
#pragma unroll
                for (int ks = 0; ks < 8; ++ks) {
                    acc[0][8 + nj] = __builtin_amdgcn_mfma_f32_16x16x32_bf16(wf[ks], aw[0][ks], acc[0][8 + nj], 0, 0, 0);
                    acc[1][8 + nj] = __builtin_amdgcn_mfma_f32_16x16x32_bf16(wf[ks], aw[1][ks], acc[1][8 + nj], 0, 0, 0);
                } break;
            default:
#pragma unroll
                for (int ks = 0; ks < 8; ++ks) {
                    acc[0][12 + nj] = __builtin_amdgcn_mfma_f32_16x16x32_bf16(wf[ks], aw[0][ks], acc[0][12 + nj], 0, 0, 0);
                    acc[1][12 + nj] = __builtin_amdgcn_mfma_f32_16x16x32_bf16(wf[ks], aw[1][ks], acc[1][12 + nj], 0, 0, 0);
                } break;
            }
        }
        __syncthreads();
    }

#pragma unroll
    for (int mi = 0; mi < 2; ++mi) {
        const int m    = m0 + wave * 32 + mi * 16 + fr;
        const int bimg = m >> 14;
        const int rem  = m & 16383;
        const int win  = rem >> 6;
        const int tok  = rem & 63;
        const int hp = (win >> 4) * 8 + (tok >> 3);
        const int wp = (win & 15) * 8 + (tok & 7);
        const int ho = (hp + SS_) & (H_ - 1);
        const int wo = (wp + SS_) & (W_ - 1);
        const size_t drow = ((size_t)(bimg << 14) + ho * W_ + wo) * 256;

        float sum = 0.0f, ssum = 0.0f;
#pragma unroll
        for (int u = 0; u < 16; ++u) {
            const int n = (u >> 2) * 64 + (u & 3) * 16 + h * 4;
            const float4 bb = *(const float4*)&bias[n];
            const float4 r4 = *(const float4*)&resid[drow + n];
            float4 v;
            v.x = acc[mi][u][0] + bb.x + r4.x;
            v.y = acc[mi][u][1] + bb.y + r4.y;
            v.z = acc[mi][u][2] + bb.z + r4.z;
            v.w = acc[mi][u][3] + bb.w + r4.w;
            uint2 pk;
            pk.x = pk2(v.x, v.y);
            pk.y = pk2(v.z, v.w);
            *(uint2*)&x1b[drow + n] = pk;
            sum  += v.x + v.y + v.z + v.w;
            ssum += v.x*v.x + v.y*v.y + v.z*v.z + v.w*v.w;
        }
        sum  += __shfl_xor(sum, 16, 64);  sum  += __shfl_xor(sum, 32, 64);
        ssum += __shfl_xor(ssum, 16, 64); ssum += __shfl_xor(ssum, 32, 64);
        const float mean = sum * (1.0f / 256.0f);
        const float rstd = rsqrtf(ssum * (1.0f / 256.0f) - mean * mean + 1e-5f);

#pragma unroll
        for (int u = 0; u < 16; ++u) {
            const int n = (u >> 2) * 64 + (u & 3) * 16 + h * 4;
            const uint2 rb = *(const uint2*)&x1b[drow + n];   // L1-hot re-read
            const float4 gg = *(const float4*)&g2[n];
            const float4 bb = *(const float4*)&b2[n];
            uint2 pk;
            pk.x = pk2((bfl(rb.x) - mean) * rstd * gg.x + bb.x,
                       (bfh(rb.x) - mean) * rstd * gg.y + bb.y);
            pk.y = pk2((bfl(rb.y) - mean) * rstd * gg.z + bb.z,
                       (bfh(rb.y) - mean) * rstd * gg.w + bb.w);
            *(uint2*)&ln2out[drow + n] = pk;
        }
    }
}

// ---------------------------------------------------------------------------
// MFMA windowed attention (unchanged — passing).
// ---------------------------------------------------------------------------
__device__ __forceinline__ int grp_(int p) { return p < (H_ - WS_) ? 0 : (p < (H_ - SS_) ? 1 : 2); }

__global__ __launch_bounds__(256) void attn_kernel(const unsigned short* __restrict__ qkv,
                                                   const float* __restrict__ rpb,
                                                   unsigned short* __restrict__ out) {
    __shared__ unsigned short P [4][64 * 72];
    __shared__ unsigned short Vt[4][32 * 72];
    __shared__ float rpb_s[232];

    const int t    = threadIdx.x;
    const int wid  = t >> 6, lane = t & 63;
    const int head = blockIdx.x & 7;
    const int win  = (blockIdx.x >> 3) * 4 + wid;
    const int fr   = lane & 15, h = lane >> 4;

    if (t < 225) rpb_s[t] = rpb[t * 8 + head];
    __syncthreads();

    const size_t qbase = (size_t)win * 64 * 768 + head * HD_;

    bf16x8 ak[4], bq[4];
#pragma unroll
    for (int ki = 0; ki < 4; ++ki)
        ak[ki] = *(const bf16x8*)&qkv[qbase + (size_t)(ki * 16 + fr) * 768 + 256 + h * 8];
#pragma unroll
    for (int qj = 0; qj < 4; ++qj)
        bq[qj] = *(const bf16x8*)&qkv[qbase + (size_t)(qj * 16 + fr) * 768 + h * 8];

    {
        const unsigned short* vrow = &qkv[qbase + (size_t)lane * 768 + 512];
#pragma unroll
        for (int dv = 0; dv < 32; dv += 8) {
            bf16x8 v8 = *(const bf16x8*)&vrow[dv];
#pragma unroll
            for (int j = 0; j < 8; ++j)
                Vt[wid][(dv + j) * 72 + lane] = ((unsigned short*)&v8)[j];
        }
    }

    f32x4 st[4][4] = {};
#pragma unroll
    for (int ki = 0; ki < 4; ++ki)
#pragma unroll
        for (int qj = 0; qj < 4; ++qj)
            st[ki][qj] = __builtin_amdgcn_mfma_f32_16x16x32_bf16(ak[ki], bq[qj], st[ki][qj], 0, 0, 0);

    const int wim = win & 255;
    const int whb = (wim >> 4) * 8, wwb = (wim & 15) * 8;
    const float qscale = 0.17677669529663687f;

#pragma unroll
    for (int qj = 0; qj < 4; ++qj) {
        const int q  = qj * 16 + fr;
        const int yq = q >> 3, xq = q & 7;
        const int gq = grp_(whb + yq) * 3 + grp_(wwb + xq);
        float s[16];
#pragma unroll
        for (int ki = 0; ki < 4; ++ki)
#pragma unroll
            for (int r = 0; r < 4; ++r) {
                const int k  = ki * 16 + h * 4 + r;
                const int yk = k >> 3, xk = k & 7;
                const int gk = grp_(whb + yk) * 3 + grp_(wwb + xk);
                float v = fmaf(st[ki][qj][r], qscale,
                               rpb_s[(yq - yk + 7) * 15 + (xq - xk + 7)]);
                if (gk != gq) v -= 100.0f;
                s[ki * 4 + r] = v;
            }
        float m = s[0];
#pragma unroll
        for (int i = 1; i < 16; ++i) m = fmaxf(m, s[i]);
        m = fmaxf(m, __shfl_xor(m, 16, 64));
        m = fmaxf(m, __shfl_xor(m, 32, 64));
        float sum = 0.0f;
#pragma unroll
        for (int i = 0; i < 16; ++i) { s[i] = __expf(s[i] - m); sum += s[i]; }
        sum += __shfl_xor(sum, 16, 64);
        sum += __shfl_xor(sum, 32, 64);
        const float rinv = __builtin_amdgcn_rcpf(sum);
#pragma unroll
        for (int ki = 0; ki < 4; ++ki)
#pragma unroll
            for (int rp = 0; rp < 4; rp += 2) {
                const unsigned int lo = f2bf(s[ki * 4 + rp]     * rinv);
                const unsigned int hi = f2bf(s[ki * 4 + rp + 1] * rinv);
                *(unsigned int*)&P[wid][q * 72 + ki * 16 + h * 4 + rp] = lo | (hi << 16);
            }
    }

    f32x4 oacc[4][2] = {};
#pragma unroll
    for (int ks = 0; ks < 2; ++ks) {
        bf16x8 pa[4], vb[2];
#pragma unroll
        for (int qi = 0; qi < 4; ++qi)
            pa[qi] = *(const bf16x8*)&P[wid][(qi * 16 + fr) * 72 + ks * 32 + h * 8];
#pragma unroll
        for (int nj = 0; nj < 2; ++nj)
            vb[nj] = *(const bf16x8*)&Vt[wid][(nj * 16 + fr) * 72 + ks * 32 + h * 8];
#pragma unroll
        for (int qi = 0; qi < 4; ++qi)
#pragma unroll
            for (int nj = 0; nj < 2; ++nj)
                oacc[qi][nj] = __builtin_amdgcn_mfma_f32_16x16x32_bf16(pa[qi], vb[nj], oacc[qi][nj], 0, 0, 0);
    }

#pragma unroll
    for (int qi = 0; qi < 4; ++qi)
#pragma unroll
        for (int nj = 0; nj < 2; ++nj)
#pragma unroll
            for (int r = 0; r < 4; ++r) {
                const int q = qi * 16 + h * 4 + r;
                const int d = nj * 16 + fr;
                out[((size_t)win * 64 + q) * C_ + head * HD_ + d] = f2bf(oacc[qi][nj][r]);
            }
}

// ---------------------------------------------------------------------------
extern "C" void kernel_launch(void* const* d_in, const int* in_sizes, int n_in,
                              void* d_out, int out_size, void* d_ws, size_t ws_size,
                              hipStream_t stream) {
    const float* x      = (const float*)d_in[0];
    const float* n1g    = (const float*)d_in[1];
    const float* n1b    = (const float*)d_in[2];
    const float* qkv_w  = (const float*)d_in[3];
    const float* qkv_b  = (const float*)d_in[4];
    const float* rpb    = (const float*)d_in[5];
    const float* proj_w = (const float*)d_in[6];
    const float* proj_b = (const float*)d_in[7];
    const float* n2g    = (const float*)d_in[8];
    const float* n2b    = (const float*)d_in[9];
    const float* fc1_w  = (const float*)d_in[10];
    const float* fc1_b  = (const float*)d_in[11];
    const float* fc2_w  = (const float*)d_in[12];
    const float* fc2_b  = (const float*)d_in[13];
    float* out = (float*)d_out;

    // workspace (bf16 elements), peak 322 MB:
    //   wq 2 MB weights | rA 64 MB (ln2out) | rB 256 MB:
    //   phase 1-2: [0..192MB) qkv, [192..256MB) attn_o
    //   phase 3-4: [0..64MB) x1b (qkv dead after attn)
    unsigned short* wq  = (unsigned short*)d_ws;
    unsigned short* rA  = wq + (1u << 20);
    unsigned short* rB  = rA + 33554432u;
    unsigned short* rB2 = rB + 100663296u;   // attn_o region
    unsigned short* x1b = rB;                // x1 bf16 (reuses dead qkv region)

    unsigned short* qkv_wb  = wq;
    unsigned short* proj_wb = wq + 196608;
    unsigned short* fc1_wb  = wq + 262144;
    unsigned short* fc2_wb  = wq + 524288;

    cvt4<<<192, 256, 0, stream>>>(qkv_w,  qkv_wb,  196608);
    cvt4<<<64,  256, 0, stream>>>(proj_w, proj_wb, 65536);
    cvt4<<<256, 256, 0, stream>>>(fc1_w,  fc1_wb,  262144);
    cvt4<<<256, 256, 0, stream>>>(fc2_w,  fc2_wb,  262144);

    // 1. fused LN1 + shift/window-gather + QKV projection (x -> rB bf16)
    ln1_qkv<768><<<MROWS / 128, 256, 0, stream>>>(x, n1g, n1b, qkv_wb, qkv_b, rB);
    // 2. windowed attention (rB -> rB2 bf16)
    attn_kernel<<<(2048 / 4) * NH_, 256, 0, stream>>>(rB, rpb, rB2);
    // 3. proj + scatter + residual + fused LN2 (rB2 -> x1b bf16, rA bf16)
    proj_ln2<<<MROWS / 128, 256, 0, stream>>>(rB2, proj_wb, proj_b, x, n2g, n2b, x1b, rA);
    // 4. fused MLP v5 (1024 thr, 16 waves): out = x1b + gelu-MLP + b2
    mlp_fused<<<MROWS / 256, 1024, 0, stream>>>(rA, fc1_wb, fc1_b, fc2_wb, fc2_b, x1b, out);
}

// Round 18
// 547.258 us; speedup vs baseline: 1.0917x; 1.0917x over previous
//
#include <hip/hip_runtime.h>
#include <hip/hip_bf16.h>
#include <math.h>

// Problem constants
#define B_   8
#define H_   128
#define W_   128
#define C_   256
#define WS_  8
#define SS_  4
#define NH_  8
#define HD_  32
#define MROWS 131072   // B * H * W tokens

typedef short bf16x8 __attribute__((ext_vector_type(8)));
typedef float f32x4  __attribute__((ext_vector_type(4)));

__device__ __forceinline__ unsigned short f2bf(float f) {
    unsigned int u = __float_as_uint(f);
    u += 0x7fffu + ((u >> 16) & 1u);          // round-to-nearest-even
    return (unsigned short)(u >> 16);
}
__device__ __forceinline__ float bfl(unsigned int u) {   // low bf16 of u -> f32
    return __uint_as_float(u << 16);
}
__device__ __forceinline__ float bfh(unsigned int u) {   // high bf16 of u -> f32
    return __uint_as_float(u & 0xffff0000u);
}

// packed f32x2 -> bf16x2 (compiler emits v_cvt_pk_bf16_f32)
__device__ __forceinline__ unsigned int pk2(float a, float b) {
    __hip_bfloat162 h = __float22bfloat162_rn(make_float2(a, b));
    unsigned int u;
    __builtin_memcpy(&u, &h, 4);
    return u;
}

// async global->LDS, 16 bytes per lane; lds dest = wave-uniform base + lane*16
__device__ __forceinline__ void gload16(const unsigned short* g, unsigned short* l) {
    __builtin_amdgcn_global_load_lds(
        (const __attribute__((address_space(1))) unsigned int*)(const void*)g,
        (__attribute__((address_space(3))) unsigned int*)(void*)l, 16, 0, 0);
}

// cheap GELU: v * sigmoid(1.702 v)  (max |err| ~0.02, inside bf16-grade budget)
__device__ __forceinline__ float fast_gelu2(float v) {
    return v * __builtin_amdgcn_rcpf(1.0f + __expf(-1.702f * v));
}

// ---------------------------------------------------------------------------
// fp32 -> bf16 conversion for ALL four weight matrices in one dispatch.
// Block ranges: [0,192) qkv_w, [192,256) proj_w, [256,512) fc1_w, [512,768) fc2_w.
// ---------------------------------------------------------------------------
__global__ __launch_bounds__(256) void cvt_all(const float* __restrict__ s0, unsigned short* __restrict__ d0,
                                               const float* __restrict__ s1, unsigned short* __restrict__ d1,
                                               const float* __restrict__ s2, unsigned short* __restrict__ d2,
                                               const float* __restrict__ s3, unsigned short* __restrict__ d3) {
    const int b = blockIdx.x;
    const float* s;
    unsigned short* d;
    int base;
    if (b < 192)      { s = s0; d = d0; base = b; }
    else if (b < 256) { s = s1; d = d1; base = b - 192; }
    else if (b < 512) { s = s2; d = d2; base = b - 256; }
    else              { s = s3; d = d3; base = b - 512; }
    const int i = (base * 256 + threadIdx.x) * 4;
    const float4 v = *(const float4*)(s + i);
    ushort4 o;
    o.x = f2bf(v.x); o.y = f2bf(v.y); o.z = f2bf(v.z); o.w = f2bf(v.w);
    *(ushort4*)(d + i) = o;
}

// ---------------------------------------------------------------------------
// FUSED LN1 + QKV GEMM (R15/R16 — passing). 256 thr, block = 128 rows, 4 waves.
// ---------------------------------------------------------------------------
template<int N>
__global__ __launch_bounds__(256, 2) void ln1_qkv(const float* __restrict__ x,
                                                  const float* __restrict__ g1,
                                                  const float* __restrict__ b1n,
                                                  const unsigned short* __restrict__ W,
                                                  const float* __restrict__ bias,
                                                  unsigned short* __restrict__ Cout) {
    __shared__ unsigned short W_lds[2][64 * 256];

    const int t    = threadIdx.x;
    const int wave = t >> 6, lane = t & 63;
    const int fr   = lane & 15, h = lane >> 4;
    const int m0   = blockIdx.x * 128;
    constexpr int NT = N / 64;

    auto stage = [&](int b, int nt) {
        const unsigned short* Wt = W + (size_t)nt * 64 * 256;
#pragma unroll
        for (int q = 0; q < 8; ++q) {
            const int d    = q * 4096 + t * 16;            // dest byte offset
            const int row  = d >> 9;
            const int colb = (d & 511) ^ ((row & 7) << 4); // swizzled source col
            gload16(Wt + (size_t)row * 256 + (colb >> 1),
                    &W_lds[b][(q * 4096 + wave * 1024) >> 1]);
        }
    };

    stage(0, 0);                 // overlaps with the LN compute below

    // --- fused LN1 + shift-gather into A fragments
    bf16x8 aw[2][8];
#pragma unroll
    for (int mi = 0; mi < 2; ++mi) {
        const int m    = m0 + wave * 32 + mi * 16 + fr;
        const int bimg = m >> 14;
        const int rem  = m & 16383;
        const int win  = rem >> 6;
        const int tok  = rem & 63;
        const int hp = (win >> 4) * 8 + (tok >> 3);
        const int wp = (win & 15) * 8 + (tok & 7);
        const int ho = (hp + SS_) & (H_ - 1);
        const int wo = (wp + SS_) & (W_ - 1);
        const float* xr = x + ((size_t)(bimg << 14) + ho * W_ + wo) * C_;

        float4 va[8], vb[8];
        float s = 0.0f, ss = 0.0f;
#pragma unroll
        for (int ks = 0; ks < 8; ++ks) {
            va[ks] = *(const float4*)&xr[ks * 32 + h * 8];
            vb[ks] = *(const float4*)&xr[ks * 32 + h * 8 + 4];
            s  += va[ks].x + va[ks].y + va[ks].z + va[ks].w
                + vb[ks].x + vb[ks].y + vb[ks].z + vb[ks].w;
            ss += va[ks].x*va[ks].x + va[ks].y*va[ks].y + va[ks].z*va[ks].z + va[ks].w*va[ks].w
                + vb[ks].x*vb[ks].x + vb[ks].y*vb[ks].y + vb[ks].z*vb[ks].z + vb[ks].w*vb[ks].w;
        }
        s  += __shfl_xor(s, 16, 64);  s  += __shfl_xor(s, 32, 64);
        ss += __shfl_xor(ss, 16, 64); ss += __shfl_xor(ss, 32, 64);
        const float mean = s * (1.0f / 256.0f);
        const float rstd = rsqrtf(ss * (1.0f / 256.0f) - mean * mean + 1e-5f);

#pragma unroll
        for (int ks = 0; ks < 8; ++ks) {
            const float4 g0 = *(const float4*)&g1 [ks * 32 + h * 8];
            const float4 g4 = *(const float4*)&g1 [ks * 32 + h * 8 + 4];
            const float4 c0 = *(const float4*)&b1n[ks * 32 + h * 8];
            const float4 c4 = *(const float4*)&b1n[ks * 32 + h * 8 + 4];
            uint4 u;
            u.x = pk2((va[ks].x - mean) * rstd * g0.x + c0.x,
                      (va[ks].y - mean) * rstd * g0.y + c0.y);
            u.y = pk2((va[ks].z - mean) * rstd * g0.z + c0.z,
                      (va[ks].w - mean) * rstd * g0.w + c0.w);
            u.z = pk2((vb[ks].x - mean) * rstd * g4.x + c4.x,
                      (vb[ks].y - mean) * rstd * g4.y + c4.y);
            u.w = pk2((vb[ks].z - mean) * rstd * g4.z + c4.z,
                      (vb[ks].w - mean) * rstd * g4.w + c4.w);
            aw[mi][ks] = *(bf16x8*)&u;
        }
    }

    __syncthreads();             // W tile 0 landed

    for (int nt = 0; nt < NT; ++nt) {
        if (nt + 1 < NT) stage((nt + 1) & 1, nt + 1);

        const char* buf = (const char*)W_lds[nt & 1];
        f32x4 acc[2][4] = {};
#pragma unroll
        for (int nj = 0; nj < 4; ++nj) {
            const int   wrow = nj * 16 + fr;
            const char* wb   = buf + wrow * 512;
            const int   swz  = (fr & 7) << 4;
            bf16x8 wf[8];
#pragma unroll
            for (int ks = 0; ks < 8; ++ks)
                wf[ks] = *(const bf16x8*)(wb + ((ks * 64 + h * 16) ^ swz));
#pragma unroll
            for (int ks = 0; ks < 8; ++ks) {
                acc[0][nj] = __builtin_amdgcn_mfma_f32_16x16x32_bf16(wf[ks], aw[0][ks], acc[0][nj], 0, 0, 0);
                acc[1][nj] = __builtin_amdgcn_mfma_f32_16x16x32_bf16(wf[ks], aw[1][ks], acc[1][nj], 0, 0, 0);
            }
        }

#pragma unroll
        for (int nj = 0; nj < 4; ++nj) {
            const int n = nt * 64 + nj * 16 + h * 4;
            const float4 bb = *(const float4*)&bias[n];
#pragma unroll
            for (int mi = 0; mi < 2; ++mi) {
                const int m = m0 + wave * 32 + mi * 16 + fr;
                uint2 pk;
                pk.x = pk2(acc[mi][nj][0] + bb.x, acc[mi][nj][1] + bb.y);
                pk.y = pk2(acc[mi][nj][2] + bb.z, acc[mi][nj][3] + bb.w);
                *(uint2*)&Cout[(size_t)m * N + n] = pk;
            }
        }
        __syncthreads();
    }
}

// ---------------------------------------------------------------------------
// Fused MLP (R13/R16-proven, 252 µs): out = bf16(x1) + gelu-MLP + b2.
// 512 thr / 8 waves, block = 256 rows, A in regs. 32 chunks of 32 FC1-cols.
// W1/W2/G all double-buffered (96 KB LDS), launch_bounds(512,2) -> VGPR 128.
// ---------------------------------------------------------------------------
__global__ __launch_bounds__(512, 2) void mlp_fused(const unsigned short* __restrict__ A,
                                                    const unsigned short* __restrict__ W1,
                                                    const float* __restrict__ b1,
                                                    const unsigned short* __restrict__ W2,
                                                    const float* __restrict__ b2,
                                                    const unsigned short* __restrict__ x1b,
                                                    float* __restrict__ out) {
    __shared__ unsigned short W1_lds[2][32 * 256];   // 2 x 16 KB
    __shared__ unsigned short W2_lds[2][256 * 32];   // 2 x 16 KB
    __shared__ unsigned short G_lds [2][256 * 32];   // 2 x 16 KB

    const int t    = threadIdx.x;
    const int wave = t >> 6, lane = t & 63;
    const int fr   = lane & 15, h = lane >> 4;
    const int wr   = wave >> 2, wc = wave & 3;       // FC2 wave grid 2x4
    const int m0   = blockIdx.x * 256;
    constexpr int NC = 32;                           // 32 chunks x 32 cols = 1024

    bf16x8 aw[2][8];
    const unsigned short* Abase = A + (size_t)(m0 + wave * 32 + fr) * 256 + h * 8;
#pragma unroll
    for (int mi = 0; mi < 2; ++mi)
#pragma unroll
        for (int ks = 0; ks < 8; ++ks)
            aw[mi][ks] = *(const bf16x8*)(Abase + mi * 16 * 256 + ks * 32);

    auto stageW1 = [&](int b, int c) {               // 32 rows x 512 B
        const unsigned short* Wt = W1 + (size_t)c * 32 * 256;
#pragma unroll
        for (int q = 0; q < 2; ++q) {
            const int d    = q * 8192 + t * 16;
            const int row  = d >> 9;
            const int colb = (d & 511) ^ ((row & 7) << 4);
            gload16(Wt + (size_t)row * 256 + (colb >> 1),
                    &W1_lds[b][(q * 8192 + wave * 1024) >> 1]);
        }
    };
    auto stageW2 = [&](int b, int c) {               // 256 rows x 64 B
#pragma unroll
        for (int q = 0; q < 2; ++q) {
            const int d    = q * 8192 + t * 16;
            const int row  = d >> 6;
            const int colb = (d & 63) ^ ((row & 3) << 4);
            gload16(W2 + (size_t)row * 1024 + c * 32 + (colb >> 1),
                    &W2_lds[b][(q * 8192 + wave * 1024) >> 1]);
        }
    };

    auto fc1 = [&](int cc, int gb) {
        const char* buf = (const char*)W1_lds[cc & 1];
        const int   swz = (fr & 7) << 4;
#pragma unroll
        for (int nj = 0; nj < 2; ++nj) {
            const int   wrow = nj * 16 + fr;
            const char* wb   = buf + wrow * 512;
            bf16x8 wf[8];
#pragma unroll
            for (int ks = 0; ks < 8; ++ks)
                wf[ks] = *(const bf16x8*)(wb + ((ks * 64 + h * 16) ^ swz));
            f32x4 g0 = {}, g1 = {};
#pragma unroll
            for (int ks = 0; ks < 8; ++ks) {
                g0 = __builtin_amdgcn_mfma_f32_16x16x32_bf16(wf[ks], aw[0][ks], g0, 0, 0, 0);
                g1 = __builtin_amdgcn_mfma_f32_16x16x32_bf16(wf[ks], aw[1][ks], g1, 0, 0, 0);
            }
            const float4 bb = *(const float4*)&b1[cc * 32 + nj * 16 + h * 4];
            {
                const int row = wave * 32 + fr;
                const int off = (nj * 32 + h * 8) ^ ((row & 3) << 4);
                uint2 pk;
                pk.x = pk2(fast_gelu2(g0[0] + bb.x), fast_gelu2(g0[1] + bb.y));
                pk.y = pk2(fast_gelu2(g0[2] + bb.z), fast_gelu2(g0[3] + bb.w));
                *(uint2*)((char*)G_lds[gb] + row * 64 + off) = pk;
            }
            {
                const int row = wave * 32 + 16 + fr;
                const int off = (nj * 32 + h * 8) ^ ((row & 3) << 4);
                uint2 pk;
                pk.x = pk2(fast_gelu2(g1[0] + bb.x), fast_gelu2(g1[1] + bb.y));
                pk.y = pk2(fast_gelu2(g1[2] + bb.z), fast_gelu2(g1[3] + bb.w));
                *(uint2*)((char*)G_lds[gb] + row * 64 + off) = pk;
            }
        }
    };

    f32x4 acc2[8][4] = {};

    // prologue
    stageW1(0, 0);
    stageW2(0, 0);
    asm volatile("s_waitcnt vmcnt(0)" ::: "memory");
    __builtin_amdgcn_sched_barrier(0);
    __builtin_amdgcn_s_barrier();
    stageW1(1, 1);
    fc1(0, 0);

    for (int c = 0; c < NC; ++c) {
        asm volatile("s_waitcnt vmcnt(0) lgkmcnt(0)" ::: "memory");
        __builtin_amdgcn_sched_barrier(0);
        __builtin_amdgcn_s_barrier();

        if (c + 2 < NC) stageW1(c & 1, c + 2);
        if (c + 1 < NC) stageW2((c + 1) & 1, c + 1);

        // ---- FC2(c): acc2 += G[c&1] @ W2[c&1]^T  (K-chunk = 32)
        {
            const char* Gb = (const char*)G_lds[c & 1];
            const char* Wb = (const char*)W2_lds[c & 1];
            bf16x8 gf[8];
#pragma unroll
            for (int mi2 = 0; mi2 < 8; ++mi2) {
                const int grow = wr * 128 + mi2 * 16 + fr;
                gf[mi2] = *(const bf16x8*)(Gb + grow * 64 + ((h * 16) ^ ((grow & 3) << 4)));
            }
#pragma unroll
            for (int nj2 = 0; nj2 < 4; ++nj2) {
                const int wrow2 = wc * 64 + nj2 * 16 + fr;
                const bf16x8 w2f = *(const bf16x8*)(Wb + wrow2 * 64 + ((h * 16) ^ ((wrow2 & 3) << 4)));
#pragma unroll
                for (int mi2 = 0; mi2 < 8; ++mi2)
                    acc2[mi2][nj2] = __builtin_amdgcn_mfma_f32_16x16x32_bf16(
                        w2f, gf[mi2], acc2[mi2][nj2], 0, 0, 0);
            }
        }

        if (c + 1 < NC) fc1(c + 1, (c + 1) & 1);
    }

    // epilogue: out[m][n] = bf16resid(x1b) + acc2 + b2  (full overwrite)
    float4 bv[4];
#pragma unroll
    for (int nj2 = 0; nj2 < 4; ++nj2)
        bv[nj2] = *(const float4*)&b2[wc * 64 + nj2 * 16 + h * 4];

#pragma unroll
    for (int mi2 = 0; mi2 < 8; ++mi2) {
        const int m = m0 + wr * 128 + mi2 * 16 + fr;
#pragma unroll
        for (int nj2 = 0; nj2 < 4; ++nj2) {
            const int n = wc * 64 + nj2 * 16 + h * 4;
            const size_t idx = (size_t)m * 256 + n;
            const uint2 rb = *(const uint2*)&x1b[idx];
            float4 o;
            o.x = acc2[mi2][nj2][0] + bv[nj2].x + bfl(rb.x);
            o.y = acc2[mi2][nj2][1] + bv[nj2].y + bfh(rb.x);
            o.z = acc2[mi2][nj2][2] + bv[nj2].z + bfl(rb.y);
            o.w = acc2[mi2][nj2][3] + bv[nj2].w + bfh(rb.y);
            *(float4*)&out[idx] = o;
        }
    }
}

// ---------------------------------------------------------------------------
// proj GEMM (K=256, N=256) + window-reverse/unshift scatter + residual +
// FUSED LayerNorm2. x1 stored as BF16 (x1b) — no fp32 out write.
// ---------------------------------------------------------------------------
__global__ __launch_bounds__(256, 2) void proj_ln2(const unsigned short* __restrict__ A,
                                                   const unsigned short* __restrict__ W,
                                                   const float* __restrict__ bias,
                                                   const float* __restrict__ resid,
                                                   const float* __restrict__ g2,
                                                   const float* __restrict__ b2,
                                                   unsigned short* __restrict__ x1b,
                                                   unsigned short* __restrict__ ln2out) {
    __shared__ unsigned short W_lds[2][64 * 256];

    const int t    = threadIdx.x;
    const int wave = t >> 6, lane = t & 63;
    const int fr   = lane & 15, h = lane >> 4;
    const int m0   = blockIdx.x * 128;

    bf16x8 aw[2][8];
    const unsigned short* Abase = A + (size_t)(m0 + wave * 32 + fr) * 256 + h * 8;
#pragma unroll
    for (int mi = 0; mi < 2; ++mi)
#pragma unroll
        for (int ks = 0; ks < 8; ++ks)
            aw[mi][ks] = *(const bf16x8*)(Abase + mi * 16 * 256 + ks * 32);

    auto stage = [&](int b, int nt) {
        const unsigned short* Wt = W + (size_t)nt * 64 * 256;
#pragma unroll
        for (int q = 0; q < 8; ++q) {
            const int d    = q * 4096 + t * 16;
            const int row  = d >> 9;
            const int colb = (d & 511) ^ ((row & 7) << 4);
            gload16(Wt + (size_t)row * 256 + (colb >> 1),
                    &W_lds[b][(q * 4096 + wave * 1024) >> 1]);
        }
    };

    stage(0, 0);
    __syncthreads();

    f32x4 acc[2][16] = {};
    for (int nt = 0; nt < 4; ++nt) {
        if (nt < 3) stage((nt + 1) & 1, nt + 1);
        const char* buf = (const char*)W_lds[nt & 1];
#pragma unroll
        for (int nj = 0; nj < 4; ++nj) {
            const int   wrow = nj * 16 + fr;
            const char* wb   = buf + wrow * 512;
            const int   swz  = (fr & 7) << 4;
            bf16x8 wf[8];
#pragma unroll
            for (int ks = 0; ks < 8; ++ks)
                wf[ks] = *(const bf16x8*)(wb + ((ks * 64 + h * 16) ^ swz));
            switch (nt) {
            case 0:
#pragma unroll
                for (int ks = 0; ks < 8; ++ks) {
                    acc[0][0 + nj] = __builtin_amdgcn_mfma_f32_16x16x32_bf16(wf[ks], aw[0][ks], acc[0][0 + nj], 0, 0, 0);
                    acc[1][0 + nj] = __builtin_amdgcn_mfma_f32_16x16x32_bf16(wf[ks], aw[1][ks], acc[1][0 + nj], 0, 0, 0);
                } break;
            case 1:
#pragma unroll
                for (int ks = 0; ks < 8; ++ks) {
                    acc[0][4 + nj] = __builtin_amdgcn_mfma_f32_16x16x32_bf16(wf[ks], aw[0][ks], acc[0][4 + nj], 0, 0, 0);
                    acc[1][4 + nj] = __builtin_amdgcn_mfma_f32_16x16x32_bf16(wf[ks], aw[1][ks], acc[1][4 + nj], 0, 0, 0);
                } break;
            case 2:
#pragma unroll
                for (int ks = 0; ks < 8; ++ks) {
                    acc[0][8 + nj] = __builtin_amdgcn_mfma_f32_16x16x32_bf16(wf[ks], aw[0][ks], acc[0][8 + nj], 0, 0, 0);
                    acc[1][8 + nj] = __builtin_amdgcn_mfma_f32_16x16x32_bf16(wf[ks], aw[1][ks], acc[1][8 + nj], 0, 0, 0);
                } break;
            default:
#pragma unroll
                for (int ks = 0; ks < 8; ++ks) {
                    acc[0][12 + nj] = __builtin_amdgcn_mfma_f32_16x16x32_bf16(wf[ks], aw[0][ks], acc[0][12 + nj], 0, 0, 0);
                    acc[1][12 + nj] = __builtin_amdgcn_mfma_f32_16x16x32_bf16(wf[ks], aw[1][ks], acc[1][12 + nj], 0, 0, 0);
                } break;
            }
        }
        __syncthreads();
    }

#pragma unroll
    for (int mi = 0; mi < 2; ++mi) {
        const int m    = m0 + wave * 32 + mi * 16 + fr;
        const int bimg = m >> 14;
        const int rem  = m & 16383;
        const int win  = rem >> 6;
        const int tok  = rem & 63;
        const int hp = (win >> 4) * 8 + (tok >> 3);
        const int wp = (win & 15) * 8 + (tok & 7);
        const int ho = (hp + SS_) & (H_ - 1);
        const int wo = (wp + SS_) & (W_ - 1);
        const size_t drow = ((size_t)(bimg << 14) + ho * W_ + wo) * 256;

        float sum = 0.0f, ssum = 0.0f;
#pragma unroll
        for (int u = 0; u < 16; ++u) {
            const int n = (u >> 2) * 64 + (u & 3) * 16 + h * 4;
            const float4 bb = *(const float4*)&bias[n];
            const float4 r4 = *(const float4*)&resid[drow + n];
            float4 v;
            v.x = acc[mi][u][0] + bb.x + r4.x;
            v.y = acc[mi][u][1] + bb.y + r4.y;
            v.z = acc[mi][u][2] + bb.z + r4.z;
            v.w = acc[mi][u][3] + bb.w + r4.w;
            uint2 pk;
            pk.x = pk2(v.x, v.y);
            pk.y = pk2(v.z, v.w);
            *(uint2*)&x1b[drow + n] = pk;
            sum  += v.x + v.y + v.z + v.w;
            ssum += v.x*v.x + v.y*v.y + v.z*v.z + v.w*v.w;
        }
        sum  += __shfl_xor(sum, 16, 64);  sum  += __shfl_xor(sum, 32, 64);
        ssum += __shfl_xor(ssum, 16, 64); ssum += __shfl_xor(ssum, 32, 64);
        const float mean = sum * (1.0f / 256.0f);
        const float rstd = rsqrtf(ssum * (1.0f / 256.0f) - mean * mean + 1e-5f);

#pragma unroll
        for (int u = 0; u < 16; ++u) {
            const int n = (u >> 2) * 64 + (u & 3) * 16 + h * 4;
            const uint2 rb = *(const uint2*)&x1b[drow + n];   // L1-hot re-read
            const float4 gg = *(const float4*)&g2[n];
            const float4 bb = *(const float4*)&b2[n];
            uint2 pk;
            pk.x = pk2((bfl(rb.x) - mean) * rstd * gg.x + bb.x,
                       (bfh(rb.x) - mean) * rstd * gg.y + bb.y);
            pk.y = pk2((bfl(rb.y) - mean) * rstd * gg.z + bb.z,
                       (bfh(rb.y) - mean) * rstd * gg.w + bb.w);
            *(uint2*)&ln2out[drow + n] = pk;
        }
    }
}

// ---------------------------------------------------------------------------
// MFMA windowed attention (unchanged — passing).
// ---------------------------------------------------------------------------
__device__ __forceinline__ int grp_(int p) { return p < (H_ - WS_) ? 0 : (p < (H_ - SS_) ? 1 : 2); }

__global__ __launch_bounds__(256) void attn_kernel(const unsigned short* __restrict__ qkv,
                                                   const float* __restrict__ rpb,
                                                   unsigned short* __restrict__ out) {
    __shared__ unsigned short P [4][64 * 72];
    __shared__ unsigned short Vt[4][32 * 72];
    __shared__ float rpb_s[232];

    const int t    = threadIdx.x;
    const int wid  = t >> 6, lane = t & 63;
    const int head = blockIdx.x & 7;
    const int win  = (blockIdx.x >> 3) * 4 + wid;
    const int fr   = lane & 15, h = lane >> 4;

    if (t < 225) rpb_s[t] = rpb[t * 8 + head];
    __syncthreads();

    const size_t qbase = (size_t)win * 64 * 768 + head * HD_;

    bf16x8 ak[4], bq[4];
#pragma unroll
    for (int ki = 0; ki < 4; ++ki)
        ak[ki] = *(const bf16x8*)&qkv[qbase + (size_t)(ki * 16 + fr) * 768 + 256 + h * 8];
#pragma unroll
    for (int qj = 0; qj < 4; ++qj)
        bq[qj] = *(const bf16x8*)&qkv[qbase + (size_t)(qj * 16 + fr) * 768 + h * 8];

    {
        const unsigned short* vrow = &qkv[qbase + (size_t)lane * 768 + 512];
#pragma unroll
        for (int dv = 0; dv < 32; dv += 8) {
            bf16x8 v8 = *(const bf16x8*)&vrow[dv];
#pragma unroll
            for (int j = 0; j < 8; ++j)
                Vt[wid][(dv + j) * 72 + lane] = ((unsigned short*)&v8)[j];
        }
    }

    f32x4 st[4][4] = {};
#pragma unroll
    for (int ki = 0; ki < 4; ++ki)
#pragma unroll
        for (int qj = 0; qj < 4; ++qj)
            st[ki][qj] = __builtin_amdgcn_mfma_f32_16x16x32_bf16(ak[ki], bq[qj], st[ki][qj], 0, 0, 0);

    const int wim = win & 255;
    const int whb = (wim >> 4) * 8, wwb = (wim & 15) * 8;
    const float qscale = 0.17677669529663687f;

#pragma unroll
    for (int qj = 0; qj < 4; ++qj) {
        const int q  = qj * 16 + fr;
        const int yq = q >> 3, xq = q & 7;
        const int gq = grp_(whb + yq) * 3 + grp_(wwb + xq);
        float s[16];
#pragma unroll
        for (int ki = 0; ki < 4; ++ki)
#pragma unroll
            for (int r = 0; r < 4; ++r) {
                const int k  = ki * 16 + h * 4 + r;
                const int yk = k >> 3, xk = k & 7;
                const int gk = grp_(whb + yk) * 3 + grp_(wwb + xk);
                float v = fmaf(st[ki][qj][r], qscale,
                               rpb_s[(yq - yk + 7) * 15 + (xq - xk + 7)]);
                if (gk != gq) v -= 100.0f;
                s[ki * 4 + r] = v;
            }
        float m = s[0];
#pragma unroll
        for (int i = 1; i < 16; ++i) m = fmaxf(m, s[i]);
        m = fmaxf(m, __shfl_xor(m, 16, 64));
        m = fmaxf(m, __shfl_xor(m, 32, 64));
        float sum = 0.0f;
#pragma unroll
        for (int i = 0; i < 16; ++i) { s[i] = __expf(s[i] - m); sum += s[i]; }
        sum += __shfl_xor(sum, 16, 64);
        sum += __shfl_xor(sum, 32, 64);
        const float rinv = __builtin_amdgcn_rcpf(sum);
#pragma unroll
        for (int ki = 0; ki < 4; ++ki)
#pragma unroll
            for (int rp = 0; rp < 4; rp += 2) {
                const unsigned int lo = f2bf(s[ki * 4 + rp]     * rinv);
                const unsigned int hi = f2bf(s[ki * 4 + rp + 1] * rinv);
                *(unsigned int*)&P[wid][q * 72 + ki * 16 + h * 4 + rp] = lo | (hi << 16);
            }
    }

    f32x4 oacc[4][2] = {};
#pragma unroll
    for (int ks = 0; ks < 2; ++ks) {
        bf16x8 pa[4], vb[2];
#pragma unroll
        for (int qi = 0; qi < 4; ++qi)
            pa[qi] = *(const bf16x8*)&P[wid][(qi * 16 + fr) * 72 + ks * 32 + h * 8];
#pragma unroll
        for (int nj = 0; nj < 2; ++nj)
            vb[nj] = *(const bf16x8*)&Vt[wid][(nj * 16 + fr) * 72 + ks * 32 + h * 8];
#pragma unroll
        for (int qi = 0; qi < 4; ++qi)
#pragma unroll
            for (int nj = 0; nj < 2; ++nj)
                oacc[qi][nj] = __builtin_amdgcn_mfma_f32_16x16x32_bf16(pa[qi], vb[nj], oacc[qi][nj], 0, 0, 0);
    }

#pragma unroll
    for (int qi = 0; qi < 4; ++qi)
#pragma unroll
        for (int nj = 0; nj < 2; ++nj)
#pragma unroll
            for (int r = 0; r < 4; ++r) {
                const int q = qi * 16 + h * 4 + r;
                const int d = nj * 16 + fr;
                out[((size_t)win * 64 + q) * C_ + head * HD_ + d] = f2bf(oacc[qi][nj][r]);
            }
}

// ---------------------------------------------------------------------------
extern "C" void kernel_launch(void* const* d_in, const int* in_sizes, int n_in,
                              void* d_out, int out_size, void* d_ws, size_t ws_size,
                              hipStream_t stream) {
    const float* x      = (const float*)d_in[0];
    const float* n1g    = (const float*)d_in[1];
    const float* n1b    = (const float*)d_in[2];
    const float* qkv_w  = (const float*)d_in[3];
    const float* qkv_b  = (const float*)d_in[4];
    const float* rpb    = (const float*)d_in[5];
    const float* proj_w = (const float*)d_in[6];
    const float* proj_b = (const float*)d_in[7];
    const float* n2g    = (const float*)d_in[8];
    const float* n2b    = (const float*)d_in[9];
    const float* fc1_w  = (const float*)d_in[10];
    const float* fc1_b  = (const float*)d_in[11];
    const float* fc2_w  = (const float*)d_in[12];
    const float* fc2_b  = (const float*)d_in[13];
    float* out = (float*)d_out;

    // workspace (bf16 elements), peak 322 MB:
    //   wq 2 MB weights | rA 64 MB (ln2out) | rB 256 MB:
    //   phase 1-2: [0..192MB) qkv, [192..256MB) attn_o
    //   phase 3-4: [0..64MB) x1b (qkv dead after attn)
    unsigned short* wq  = (unsigned short*)d_ws;
    unsigned short* rA  = wq + (1u << 20);
    unsigned short* rB  = rA + 33554432u;
    unsigned short* rB2 = rB + 100663296u;   // attn_o region
    unsigned short* x1b = rB;                // x1 bf16 (reuses dead qkv region)

    unsigned short* qkv_wb  = wq;
    unsigned short* proj_wb = wq + 196608;
    unsigned short* fc1_wb  = wq + 262144;
    unsigned short* fc2_wb  = wq + 524288;

    // 0. all weight conversions in one dispatch
    cvt_all<<<768, 256, 0, stream>>>(qkv_w, qkv_wb, proj_w, proj_wb,
                                     fc1_w, fc1_wb, fc2_w, fc2_wb);

    // 1. fused LN1 + shift/window-gather + QKV projection (x -> rB bf16)
    ln1_qkv<768><<<MROWS / 128, 256, 0, stream>>>(x, n1g, n1b, qkv_wb, qkv_b, rB);
    // 2. windowed attention (rB -> rB2 bf16)
    attn_kernel<<<(2048 / 4) * NH_, 256, 0, stream>>>(rB, rpb, rB2);
    // 3. proj + scatter + residual + fused LN2 (rB2 -> x1b bf16, rA bf16)
    proj_ln2<<<MROWS / 128, 256, 0, stream>>>(rB2, proj_wb, proj_b, x, n2g, n2b, x1b, rA);
    // 4. fused MLP (R13/R16): out = x1b + gelu(rA @ W1^T + b1) @ W2^T + b2
    mlp_fused<<<MROWS / 256, 512, 0, stream>>>(rA, fc1_wb, fc1_b, fc2_wb, fc2_b, x1b, out);
}

// Round 19
// 546.304 us; speedup vs baseline: 1.0936x; 1.0017x over previous
//
#include <hip/hip_runtime.h>
#include <hip/hip_bf16.h>
#include <math.h>

// Problem constants
#define B_   8
#define H_   128
#define W_   128
#define C_   256
#define WS_  8
#define SS_  4
#define NH_  8
#define HD_  32
#define MROWS 131072   // B * H * W tokens

typedef short bf16x8 __attribute__((ext_vector_type(8)));
typedef float f32x4  __attribute__((ext_vector_type(4)));

__device__ __forceinline__ unsigned short f2bf(float f) {
    unsigned int u = __float_as_uint(f);
    u += 0x7fffu + ((u >> 16) & 1u);          // round-to-nearest-even
    return (unsigned short)(u >> 16);
}
__device__ __forceinline__ float bfl(unsigned int u) {   // low bf16 of u -> f32
    return __uint_as_float(u << 16);
}
__device__ __forceinline__ float bfh(unsigned int u) {   // high bf16 of u -> f32
    return __uint_as_float(u & 0xffff0000u);
}

// packed f32x2 -> bf16x2 (compiler emits v_cvt_pk_bf16_f32)
__device__ __forceinline__ unsigned int pk2(float a, float b) {
    __hip_bfloat162 h = __float22bfloat162_rn(make_float2(a, b));
    unsigned int u;
    __builtin_memcpy(&u, &h, 4);
    return u;
}

// async global->LDS, 16 bytes per lane; lds dest = wave-uniform base + lane*16
__device__ __forceinline__ void gload16(const unsigned short* g, unsigned short* l) {
    __builtin_amdgcn_global_load_lds(
        (const __attribute__((address_space(1))) unsigned int*)(const void*)g,
        (__attribute__((address_space(3))) unsigned int*)(void*)l, 16, 0, 0);
}

// cheap GELU: v * sigmoid(1.702 v)  (max |err| ~0.02, inside bf16-grade budget)
__device__ __forceinline__ float fast_gelu2(float v) {
    return v * __builtin_amdgcn_rcpf(1.0f + __expf(-1.702f * v));
}

// ---------------------------------------------------------------------------
// fp32 -> bf16 conversion for ALL four weight matrices in one dispatch.
// Block ranges: [0,192) qkv_w, [192,256) proj_w, [256,512) fc1_w, [512,768) fc2_w.
// ---------------------------------------------------------------------------
__global__ __launch_bounds__(256) void cvt_all(const float* __restrict__ s0, unsigned short* __restrict__ d0,
                                               const float* __restrict__ s1, unsigned short* __restrict__ d1,
                                               const float* __restrict__ s2, unsigned short* __restrict__ d2,
                                               const float* __restrict__ s3, unsigned short* __restrict__ d3) {
    const int b = blockIdx.x;
    const float* s;
    unsigned short* d;
    int base;
    if (b < 192)      { s = s0; d = d0; base = b; }
    else if (b < 256) { s = s1; d = d1; base = b - 192; }
    else if (b < 512) { s = s2; d = d2; base = b - 256; }
    else              { s = s3; d = d3; base = b - 512; }
    const int i = (base * 256 + threadIdx.x) * 4;
    const float4 v = *(const float4*)(s + i);
    ushort4 o;
    o.x = f2bf(v.x); o.y = f2bf(v.y); o.z = f2bf(v.z); o.w = f2bf(v.w);
    *(ushort4*)(d + i) = o;
}

// ---------------------------------------------------------------------------
// FUSED LN1 + QKV GEMM (R15/R16 — passing). 256 thr, block = 128 rows, 4 waves.
// ---------------------------------------------------------------------------
template<int N>
__global__ __launch_bounds__(256, 2) void ln1_qkv(const float* __restrict__ x,
                                                  const float* __restrict__ g1,
                                                  const float* __restrict__ b1n,
                                                  const unsigned short* __restrict__ W,
                                                  const float* __restrict__ bias,
                                                  unsigned short* __restrict__ Cout) {
    __shared__ unsigned short W_lds[2][64 * 256];

    const int t    = threadIdx.x;
    const int wave = t >> 6, lane = t & 63;
    const int fr   = lane & 15, h = lane >> 4;
    const int m0   = blockIdx.x * 128;
    constexpr int NT = N / 64;

    auto stage = [&](int b, int nt) {
        const unsigned short* Wt = W + (size_t)nt * 64 * 256;
#pragma unroll
        for (int q = 0; q < 8; ++q) {
            const int d    = q * 4096 + t * 16;            // dest byte offset
            const int row  = d >> 9;
            const int colb = (d & 511) ^ ((row & 7) << 4); // swizzled source col
            gload16(Wt + (size_t)row * 256 + (colb >> 1),
                    &W_lds[b][(q * 4096 + wave * 1024) >> 1]);
        }
    };

    stage(0, 0);                 // overlaps with the LN compute below

    // --- fused LN1 + shift-gather into A fragments
    bf16x8 aw[2][8];
#pragma unroll
    for (int mi = 0; mi < 2; ++mi) {
        const int m    = m0 + wave * 32 + mi * 16 + fr;
        const int bimg = m >> 14;
        const int rem  = m & 16383;
        const int win  = rem >> 6;
        const int tok  = rem & 63;
        const int hp = (win >> 4) * 8 + (tok >> 3);
        const int wp = (win & 15) * 8 + (tok & 7);
        const int ho = (hp + SS_) & (H_ - 1);
        const int wo = (wp + SS_) & (W_ - 1);
        const float* xr = x + ((size_t)(bimg << 14) + ho * W_ + wo) * C_;

        float4 va[8], vb[8];
        float s = 0.0f, ss = 0.0f;
#pragma unroll
        for (int ks = 0; ks < 8; ++ks) {
            va[ks] = *(const float4*)&xr[ks * 32 + h * 8];
            vb[ks] = *(const float4*)&xr[ks * 32 + h * 8 + 4];
            s  += va[ks].x + va[ks].y + va[ks].z + va[ks].w
                + vb[ks].x + vb[ks].y + vb[ks].z + vb[ks].w;
            ss += va[ks].x*va[ks].x + va[ks].y*va[ks].y + va[ks].z*va[ks].z + va[ks].w*va[ks].w
                + vb[ks].x*vb[ks].x + vb[ks].y*vb[ks].y + vb[ks].z*vb[ks].z + vb[ks].w*vb[ks].w;
        }
        s  += __shfl_xor(s, 16, 64);  s  += __shfl_xor(s, 32, 64);
        ss += __shfl_xor(ss, 16, 64); ss += __shfl_xor(ss, 32, 64);
        const float mean = s * (1.0f / 256.0f);
        const float rstd = rsqrtf(ss * (1.0f / 256.0f) - mean * mean + 1e-5f);

#pragma unroll
        for (int ks = 0; ks < 8; ++ks) {
            const float4 g0 = *(const float4*)&g1 [ks * 32 + h * 8];
            const float4 g4 = *(const float4*)&g1 [ks * 32 + h * 8 + 4];
            const float4 c0 = *(const float4*)&b1n[ks * 32 + h * 8];
            const float4 c4 = *(const float4*)&b1n[ks * 32 + h * 8 + 4];
            uint4 u;
            u.x = pk2((va[ks].x - mean) * rstd * g0.x + c0.x,
                      (va[ks].y - mean) * rstd * g0.y + c0.y);
            u.y = pk2((va[ks].z - mean) * rstd * g0.z + c0.z,
                      (va[ks].w - mean) * rstd * g0.w + c0.w);
            u.z = pk2((vb[ks].x - mean) * rstd * g4.x + c4.x,
                      (vb[ks].y - mean) * rstd * g4.y + c4.y);
            u.w = pk2((vb[ks].z - mean) * rstd * g4.z + c4.z,
                      (vb[ks].w - mean) * rstd * g4.w + c4.w);
            aw[mi][ks] = *(bf16x8*)&u;
        }
    }

    __syncthreads();             // W tile 0 landed

    for (int nt = 0; nt < NT; ++nt) {
        if (nt + 1 < NT) stage((nt + 1) & 1, nt + 1);

        const char* buf = (const char*)W_lds[nt & 1];
        f32x4 acc[2][4] = {};
#pragma unroll
        for (int nj = 0; nj < 4; ++nj) {
            const int   wrow = nj * 16 + fr;
            const char* wb   = buf + wrow * 512;
            const int   swz  = (fr & 7) << 4;
            bf16x8 wf[8];
#pragma unroll
            for (int ks = 0; ks < 8; ++ks)
                wf[ks] = *(const bf16x8*)(wb + ((ks * 64 + h * 16) ^ swz));
#pragma unroll
            for (int ks = 0; ks < 8; ++ks) {
                acc[0][nj] = __builtin_amdgcn_mfma_f32_16x16x32_bf16(wf[ks], aw[0][ks], acc[0][nj], 0, 0, 0);
                acc[1][nj] = __builtin_amdgcn_mfma_f32_16x16x32_bf16(wf[ks], aw[1][ks], acc[1][nj], 0, 0, 0);
            }
        }

#pragma unroll
        for (int nj = 0; nj < 4; ++nj) {
            const int n = nt * 64 + nj * 16 + h * 4;
            const float4 bb = *(const float4*)&bias[n];
#pragma unroll
            for (int mi = 0; mi < 2; ++mi) {
                const int m = m0 + wave * 32 + mi * 16 + fr;
                uint2 pk;
                pk.x = pk2(acc[mi][nj][0] + bb.x, acc[mi][nj][1] + bb.y);
                pk.y = pk2(acc[mi][nj][2] + bb.z, acc[mi][nj][3] + bb.w);
                *(uint2*)&Cout[(size_t)m * N + n] = pk;
            }
        }
        __syncthreads();
    }
}

// ---------------------------------------------------------------------------
// Fused MLP (R13/R16 schedule; R19: G/W2 swizzle ((row>>2)&3)<<4 — the read
// conflict set is rows differing by 4 (256 B = 0 mod 32 banks), which the
// old (row&3) swizzle could not separate; rows differing by 2 become 2-way
// aliasing, which is free. Same involution at stage source, G write, reads.
// 512 thr / 8 waves, block = 256 rows, A in regs. 32 chunks of 32 FC1-cols.
// W1/W2/G all double-buffered (96 KB LDS), launch_bounds(512,2) -> VGPR 128.
// ---------------------------------------------------------------------------
__global__ __launch_bounds__(512, 2) void mlp_fused(const unsigned short* __restrict__ A,
                                                    const unsigned short* __restrict__ W1,
                                                    const float* __restrict__ b1,
                                                    const unsigned short* __restrict__ W2,
                                                    const float* __restrict__ b2,
                                                    const unsigned short* __restrict__ x1b,
                                                    float* __restrict__ out) {
    __shared__ unsigned short W1_lds[2][32 * 256];   // 2 x 16 KB
    __shared__ unsigned short W2_lds[2][256 * 32];   // 2 x 16 KB
    __shared__ unsigned short G_lds [2][256 * 32];   // 2 x 16 KB

    const int t    = threadIdx.x;
    const int wave = t >> 6, lane = t & 63;
    const int fr   = lane & 15, h = lane >> 4;
    const int wr   = wave >> 2, wc = wave & 3;       // FC2 wave grid 2x4
    const int m0   = blockIdx.x * 256;
    constexpr int NC = 32;                           // 32 chunks x 32 cols = 1024

    bf16x8 aw[2][8];
    const unsigned short* Abase = A + (size_t)(m0 + wave * 32 + fr) * 256 + h * 8;
#pragma unroll
    for (int mi = 0; mi < 2; ++mi)
#pragma unroll
        for (int ks = 0; ks < 8; ++ks)
            aw[mi][ks] = *(const bf16x8*)(Abase + mi * 16 * 256 + ks * 32);

    auto stageW1 = [&](int b, int c) {               // 32 rows x 512 B
        const unsigned short* Wt = W1 + (size_t)c * 32 * 256;
#pragma unroll
        for (int q = 0; q < 2; ++q) {
            const int d    = q * 8192 + t * 16;
            const int row  = d >> 9;
            const int colb = (d & 511) ^ ((row & 7) << 4);
            gload16(Wt + (size_t)row * 256 + (colb >> 1),
                    &W1_lds[b][(q * 8192 + wave * 1024) >> 1]);
        }
    };
    auto stageW2 = [&](int b, int c) {               // 256 rows x 64 B
#pragma unroll
        for (int q = 0; q < 2; ++q) {
            const int d    = q * 8192 + t * 16;
            const int row  = d >> 6;
            const int colb = (d & 63) ^ (((row >> 2) & 3) << 4);   // R19 swizzle
            gload16(W2 + (size_t)row * 1024 + c * 32 + (colb >> 1),
                    &W2_lds[b][(q * 8192 + wave * 1024) >> 1]);
        }
    };

    auto fc1 = [&](int cc, int gb) {
        const char* buf = (const char*)W1_lds[cc & 1];
        const int   swz = (fr & 7) << 4;
#pragma unroll
        for (int nj = 0; nj < 2; ++nj) {
            const int   wrow = nj * 16 + fr;
            const char* wb   = buf + wrow * 512;
            bf16x8 wf[8];
#pragma unroll
            for (int ks = 0; ks < 8; ++ks)
                wf[ks] = *(const bf16x8*)(wb + ((ks * 64 + h * 16) ^ swz));
            f32x4 g0 = {}, g1 = {};
#pragma unroll
            for (int ks = 0; ks < 8; ++ks) {
                g0 = __builtin_amdgcn_mfma_f32_16x16x32_bf16(wf[ks], aw[0][ks], g0, 0, 0, 0);
                g1 = __builtin_amdgcn_mfma_f32_16x16x32_bf16(wf[ks], aw[1][ks], g1, 0, 0, 0);
            }
            const float4 bb = *(const float4*)&b1[cc * 32 + nj * 16 + h * 4];
            {
                const int row = wave * 32 + fr;
                const int off = (nj * 32 + h * 8) ^ (((row >> 2) & 3) << 4);   // R19
                uint2 pk;
                pk.x = pk2(fast_gelu2(g0[0] + bb.x), fast_gelu2(g0[1] + bb.y));
                pk.y = pk2(fast_gelu2(g0[2] + bb.z), fast_gelu2(g0[3] + bb.w));
                *(uint2*)((char*)G_lds[gb] + row * 64 + off) = pk;
            }
            {
                const int row = wave * 32 + 16 + fr;
                const int off = (nj * 32 + h * 8) ^ (((row >> 2) & 3) << 4);   // R19
                uint2 pk;
                pk.x = pk2(fast_gelu2(g1[0] + bb.x), fast_gelu2(g1[1] + bb.y));
                pk.y = pk2(fast_gelu2(g1[2] + bb.z), fast_gelu2(g1[3] + bb.w));
                *(uint2*)((char*)G_lds[gb] + row * 64 + off) = pk;
            }
        }
    };

    f32x4 acc2[8][4] = {};

    // prologue
    stageW1(0, 0);
    stageW2(0, 0);
    asm volatile("s_waitcnt vmcnt(0)" ::: "memory");
    __builtin_amdgcn_sched_barrier(0);
    __builtin_amdgcn_s_barrier();
    stageW1(1, 1);
    fc1(0, 0);

    for (int c = 0; c < NC; ++c) {
        asm volatile("s_waitcnt vmcnt(0) lgkmcnt(0)" ::: "memory");
        __builtin_amdgcn_sched_barrier(0);
        __builtin_amdgcn_s_barrier();

        if (c + 2 < NC) stageW1(c & 1, c + 2);
        if (c + 1 < NC) stageW2((c + 1) & 1, c + 1);

        // ---- FC2(c): acc2 += G[c&1] @ W2[c&1]^T  (K-chunk = 32)
        {
            const char* Gb = (const char*)G_lds[c & 1];
            const char* Wb = (const char*)W2_lds[c & 1];
            bf16x8 gf[8];
#pragma unroll
            for (int mi2 = 0; mi2 < 8; ++mi2) {
                const int grow = wr * 128 + mi2 * 16 + fr;
                gf[mi2] = *(const bf16x8*)(Gb + grow * 64 + ((h * 16) ^ (((grow >> 2) & 3) << 4)));  // R19
            }
#pragma unroll
            for (int nj2 = 0; nj2 < 4; ++nj2) {
                const int wrow2 = wc * 64 + nj2 * 16 + fr;
                const bf16x8 w2f = *(const bf16x8*)(Wb + wrow2 * 64 + ((h * 16) ^ (((wrow2 >> 2) & 3) << 4)));  // R19
#pragma unroll
                for (int mi2 = 0; mi2 < 8; ++mi2)
                    acc2[mi2][nj2] = __builtin_amdgcn_mfma_f32_16x16x32_bf16(
                        w2f, gf[mi2], acc2[mi2][nj2], 0, 0, 0);
            }
        }

        if (c + 1 < NC) fc1(c + 1, (c + 1) & 1);
    }

    // epilogue: out[m][n] = bf16resid(x1b) + acc2 + b2  (full overwrite)
    float4 bv[4];
#pragma unroll
    for (int nj2 = 0; nj2 < 4; ++nj2)
        bv[nj2] = *(const float4*)&b2[wc * 64 + nj2 * 16 + h * 4];

#pragma unroll
    for (int mi2 = 0; mi2 < 8; ++mi2) {
        const int m = m0 + wr * 128 + mi2 * 16 + fr;
#pragma unroll
        for (int nj2 = 0; nj2 < 4; ++nj2) {
            const int n = wc * 64 + nj2 * 16 + h * 4;
            const size_t idx = (size_t)m * 256 + n;
            const uint2 rb = *(const uint2*)&x1b[idx];
            float4 o;
            o.x = acc2[mi2][nj2][0] + bv[nj2].x + bfl(rb.x);
            o.y = acc2[mi2][nj2][1] + bv[nj2].y + bfh(rb.x);
            o.z = acc2[mi2][nj2][2] + bv[nj2].z + bfl(rb.y);
            o.w = acc2[mi2][nj2][3] + bv[nj2].w + bfh(rb.y);
            *(float4*)&out[idx] = o;
        }
    }
}

// ---------------------------------------------------------------------------
// proj GEMM (K=256, N=256) + window-reverse/unshift scatter + residual +
// FUSED LayerNorm2. x1 stored as BF16 (x1b) — no fp32 out write.
// ---------------------------------------------------------------------------
__global__ __launch_bounds__(256, 2) void proj_ln2(const unsigned short* __restrict__ A,
                                                   const unsigned short* __restrict__ W,
                                                   const float* __restrict__ bias,
                                                   const float* __restrict__ resid,
                                                   const float* __restrict__ g2,
                                                   const float* __restrict__ b2,
                                                   unsigned short* __restrict__ x1b,
                                                   unsigned short* __restrict__ ln2out) {
    __shared__ unsigned short W_lds[2][64 * 256];

    const int t    = threadIdx.x;
    const int wave = t >> 6, lane = t & 63;
    const int fr   = lane & 15, h = lane >> 4;
    const int m0   = blockIdx.x * 128;

    bf16x8 aw[2][8];
    const unsigned short* Abase = A + (size_t)(m0 + wave * 32 + fr) * 256 + h * 8;
#pragma unroll
    for (int mi = 0; mi < 2; ++mi)
#pragma unroll
        for (int ks = 0; ks < 8; ++ks)
            aw[mi][ks] = *(const bf16x8*)(Abase + mi * 16 * 256 + ks * 32);

    auto stage = [&](int b, int nt) {
        const unsigned short* Wt = W + (size_t)nt * 64 * 256;
#pragma unroll
        for (int q = 0; q < 8; ++q) {
            const int d    = q * 4096 + t * 16;
            const int row  = d >> 9;
            const int colb = (d & 511) ^ ((row & 7) << 4);
            gload16(Wt + (size_t)row * 256 + (colb >> 1),
                    &W_lds[b][(q * 4096 + wave * 1024) >> 1]);
        }
    };

    stage(0, 0);
    __syncthreads();

    f32x4 acc[2][16] = {};
    for (int nt = 0; nt < 4; ++nt) {
        if (nt < 3) stage((nt + 1) & 1, nt + 1);
        const char* buf = (const char*)W_lds[nt & 1];
#pragma unroll
        for (int nj = 0; nj < 4; ++nj) {
            const int   wrow = nj * 16 + fr;
            const char* wb   = buf + wrow * 512;
            const int   swz  = (fr & 7) << 4;
            bf16x8 wf[8];
#pragma unroll
            for (int ks = 0; ks < 8; ++ks)
                wf[ks] = *(const bf16x8*)(wb + ((ks * 64 + h * 16) ^ swz));
            switch (nt) {
            case 0:
#pragma unroll
                for (int ks = 0; ks < 8; ++ks) {
                    acc[0][0 + nj] = __builtin_amdgcn_mfma_f32_16x16x32_bf16(wf[ks], aw[0][ks], acc[0][0 + nj], 0, 0, 0);
                    acc[1][0 + nj] = __builtin_amdgcn_mfma_f32_16x16x32_bf16(wf[ks], aw[1][ks], acc[1][0 + nj], 0, 0, 0);
                } break;
            case 1:
#pragma unroll
                for (int ks = 0; ks < 8; ++ks) {
                    acc[0][4 + nj] = __builtin_amdgcn_mfma_f32_16x16x32_bf16(wf[ks], aw[0][ks], acc[0][4 + nj], 0, 0, 0);
                    acc[1][4 + nj] = __builtin_amdgcn_mfma_f32_16x16x32_bf16(wf[ks], aw[1][ks], acc[1][4 + nj], 0, 0, 0);
                } break;
            case 2:
#pragma unroll
                for (int ks = 0; ks < 8; ++ks) {
                    acc[0][8 + nj] = __builtin_amdgcn_mfma_f32_16x16x32_bf16(wf[ks], aw[0][ks], acc[0][8 + nj], 0, 0, 0);
                    acc[1][8 + nj] = __builtin_amdgcn_mfma_f32_16x16x32_bf16(wf[ks], aw[1][ks], acc[1][8 + nj], 0, 0, 0);
                } break;
            default:
#pragma unroll
                for (int ks = 0; ks < 8; ++ks) {
                    acc[0][12 + nj] = __builtin_amdgcn_mfma_f32_16x16x32_bf16(wf[ks], aw[0][ks], acc[0][12 + nj], 0, 0, 0);
                    acc[1][12 + nj] = __builtin_amdgcn_mfma_f32_16x16x32_bf16(wf[ks], aw[1][ks], acc[1][12 + nj], 0, 0, 0);
                } break;
            }
        }
        __syncthreads();
    }

#pragma unroll
    for (int mi = 0; mi < 2; ++mi) {
        const int m    = m0 + wave * 32 + mi * 16 + fr;
        const int bimg = m >> 14;
        const int rem  = m & 16383;
        const int win  = rem >> 6;
        const int tok  = rem & 63;
        const int hp = (win >> 4) * 8 + (tok >> 3);
        const int wp = (win & 15) * 8 + (tok & 7);
        const int ho = (hp + SS_) & (H_ - 1);
        const int wo = (wp + SS_) & (W_ - 1);
        const size_t drow = ((size_t)(bimg << 14) + ho * W_ + wo) * 256;

        float sum = 0.0f, ssum = 0.0f;
#pragma unroll
        for (int u = 0; u < 16; ++u) {
            const int n = (u >> 2) * 64 + (u & 3) * 16 + h * 4;
            const float4 bb = *(const float4*)&bias[n];
            const float4 r4 = *(const float4*)&resid[drow + n];
            float4 v;
            v.x = acc[mi][u][0] + bb.x + r4.x;
            v.y = acc[mi][u][1] + bb.y + r4.y;
            v.z = acc[mi][u][2] + bb.z + r4.z;
            v.w = acc[mi][u][3] + bb.w + r4.w;
            uint2 pk;
            pk.x = pk2(v.x, v.y);
            pk.y = pk2(v.z, v.w);
            *(uint2*)&x1b[drow + n] = pk;
            sum  += v.x + v.y + v.z + v.w;
            ssum += v.x*v.x + v.y*v.y + v.z*v.z + v.w*v.w;
        }
        sum  += __shfl_xor(sum, 16, 64);  sum  += __shfl_xor(sum, 32, 64);
        ssum += __shfl_xor(ssum, 16, 64); ssum += __shfl_xor(ssum, 32, 64);
        const float mean = sum * (1.0f / 256.0f);
        const float rstd = rsqrtf(ssum * (1.0f / 256.0f) - mean * mean + 1e-5f);

#pragma unroll
        for (int u = 0; u < 16; ++u) {
            const int n = (u >> 2) * 64 + (u & 3) * 16 + h * 4;
            const uint2 rb = *(const uint2*)&x1b[drow + n];   // L1-hot re-read
            const float4 gg = *(const float4*)&g2[n];
            const float4 bb = *(const float4*)&b2[n];
            uint2 pk;
            pk.x = pk2((bfl(rb.x) - mean) * rstd * gg.x + bb.x,
                       (bfh(rb.x) - mean) * rstd * gg.y + bb.y);
            pk.y = pk2((bfl(rb.y) - mean) * rstd * gg.z + bb.z,
                       (bfh(rb.y) - mean) * rstd * gg.w + bb.w);
            *(uint2*)&ln2out[drow + n] = pk;
        }
    }
}

// ---------------------------------------------------------------------------
// MFMA windowed attention (unchanged — passing).
// ---------------------------------------------------------------------------
__device__ __forceinline__ int grp_(int p) { return p < (H_ - WS_) ? 0 : (p < (H_ - SS_) ? 1 : 2); }

__global__ __launch_bounds__(256) void attn_kernel(const unsigned short* __restrict__ qkv,
                                                   const float* __restrict__ rpb,
                                                   unsigned short* __restrict__ out) {
    __shared__ unsigned short P [4][64 * 72];
    __shared__ unsigned short Vt[4][32 * 72];
    __shared__ float rpb_s[232];

    const int t    = threadIdx.x;
    const int wid  = t >> 6, lane = t & 63;
    const int head = blockIdx.x & 7;
    const int win  = (blockIdx.x >> 3) * 4 + wid;
    const int fr   = lane & 15, h = lane >> 4;

    if (t < 225) rpb_s[t] = rpb[t * 8 + head];
    __syncthreads();

    const size_t qbase = (size_t)win * 64 * 768 + head * HD_;

    bf16x8 ak[4], bq[4];
#pragma unroll
    for (int ki = 0; ki < 4; ++ki)
        ak[ki] = *(const bf16x8*)&qkv[qbase + (size_t)(ki * 16 + fr) * 768 + 256 + h * 8];
#pragma unroll
    for (int qj = 0; qj < 4; ++qj)
        bq[qj] = *(const bf16x8*)&qkv[qbase + (size_t)(qj * 16 + fr) * 768 + h * 8];

    {
        const unsigned short* vrow = &qkv[qbase + (size_t)lane * 768 + 512];
#pragma unroll
        for (int dv = 0; dv < 32; dv += 8) {
            bf16x8 v8 = *(const bf16x8*)&vrow[dv];
#pragma unroll
            for (int j = 0; j < 8; ++j)
                Vt[wid][(dv + j) * 72 + lane] = ((unsigned short*)&v8)[j];
        }
    }

    f32x4 st[4][4] = {};
#pragma unroll
    for (int ki = 0; ki < 4; ++ki)
#pragma unroll
        for (int qj = 0; qj < 4; ++qj)
            st[ki][qj] = __builtin_amdgcn_mfma_f32_16x16x32_bf16(ak[ki], bq[qj], st[ki][qj], 0, 0, 0);

    const int wim = win & 255;
    const int whb = (wim >> 4) * 8, wwb = (wim & 15) * 8;
    const float qscale = 0.17677669529663687f;

#pragma unroll
    for (int qj = 0; qj < 4; ++qj) {
        const int q  = qj * 16 + fr;
        const int yq = q >> 3, xq = q & 7;
        const int gq = grp_(whb + yq) * 3 + grp_(wwb + xq);
        float s[16];
#pragma unroll
        for (int ki = 0; ki < 4; ++ki)
#pragma unroll
            for (int r = 0; r < 4; ++r) {
                const int k  = ki * 16 + h * 4 + r;
                const int yk = k >> 3, xk = k & 7;
                const int gk = grp_(whb + yk) * 3 + grp_(wwb + xk);
                float v = fmaf(st[ki][qj][r], qscale,
                               rpb_s[(yq - yk + 7) * 15 + (xq - xk + 7)]);
                if (gk != gq) v -= 100.0f;
                s[ki * 4 + r] = v;
            }
        float m = s[0];
#pragma unroll
        for (int i = 1; i < 16; ++i) m = fmaxf(m, s[i]);
        m = fmaxf(m, __shfl_xor(m, 16, 64));
        m = fmaxf(m, __shfl_xor(m, 32, 64));
        float sum = 0.0f;
#pragma unroll
        for (int i = 0; i < 16; ++i) { s[i] = __expf(s[i] - m); sum += s[i]; }
        sum += __shfl_xor(sum, 16, 64);
        sum += __shfl_xor(sum, 32, 64);
        const float rinv = __builtin_amdgcn_rcpf(sum);
#pragma unroll
        for (int ki = 0; ki < 4; ++ki)
#pragma unroll
            for (int rp = 0; rp < 4; rp += 2) {
                const unsigned int lo = f2bf(s[ki * 4 + rp]     * rinv);
                const unsigned int hi = f2bf(s[ki * 4 + rp + 1] * rinv);
                *(unsigned int*)&P[wid][q * 72 + ki * 16 + h * 4 + rp] = lo | (hi << 16);
            }
    }

    f32x4 oacc[4][2] = {};
#pragma unroll
    for (int ks = 0; ks < 2; ++ks) {
        bf16x8 pa[4], vb[2];
#pragma unroll
        for (int qi = 0; qi < 4; ++qi)
            pa[qi] = *(const bf16x8*)&P[wid][(qi * 16 + fr) * 72 + ks * 32 + h * 8];
#pragma unroll
        for (int nj = 0; nj < 2; ++nj)
            vb[nj] = *(const bf16x8*)&Vt[wid][(nj * 16 + fr) * 72 + ks * 32 + h * 8];
#pragma unroll
        for (int qi = 0; qi < 4; ++qi)
#pragma unroll
            for (int nj = 0; nj < 2; ++nj)
                oacc[qi][nj] = __builtin_amdgcn_mfma_f32_16x16x32_bf16(pa[qi], vb[nj], oacc[qi][nj], 0, 0, 0);
    }

#pragma unroll
    for (int qi = 0; qi < 4; ++qi)
#pragma unroll
        for (int nj = 0; nj < 2; ++nj)
#pragma unroll
            for (int r = 0; r < 4; ++r) {
                const int q = qi * 16 + h * 4 + r;
                const int d = nj * 16 + fr;
                out[((size_t)win * 64 + q) * C_ + head * HD_ + d] = f2bf(oacc[qi][nj][r]);
            }
}

// ---------------------------------------------------------------------------
extern "C" void kernel_launch(void* const* d_in, const int* in_sizes, int n_in,
                              void* d_out, int out_size, void* d_ws, size_t ws_size,
                              hipStream_t stream) {
    const float* x      = (const float*)d_in[0];
    const float* n1g    = (const float*)d_in[1];
    const float* n1b    = (const float*)d_in[2];
    const float* qkv_w  = (const float*)d_in[3];
    const float* qkv_b  = (const float*)d_in[4];
    const float* rpb    = (const float*)d_in[5];
    const float* proj_w = (const float*)d_in[6];
    const float* proj_b = (const float*)d_in[7];
    const float* n2g    = (const float*)d_in[8];
    const float* n2b    = (const float*)d_in[9];
    const float* fc1_w  = (const float*)d_in[10];
    const float* fc1_b  = (const float*)d_in[11];
    const float* fc2_w  = (const float*)d_in[12];
    const float* fc2_b  = (const float*)d_in[13];
    float* out = (float*)d_out;

    // workspace (bf16 elements), peak 322 MB:
    //   wq 2 MB weights | rA 64 MB (ln2out) | rB 256 MB:
    //   phase 1-2: [0..192MB) qkv, [192..256MB) attn_o
    //   phase 3-4: [0..64MB) x1b (qkv dead after attn)
    unsigned short* wq  = (unsigned short*)d_ws;
    unsigned short* rA  = wq + (1u << 20);
    unsigned short* rB  = rA + 33554432u;
    unsigned short* rB2 = rB + 100663296u;   // attn_o region
    unsigned short* x1b = rB;                // x1 bf16 (reuses dead qkv region)

    unsigned short* qkv_wb  = wq;
    unsigned short* proj_wb = wq + 196608;
    unsigned short* fc1_wb  = wq + 262144;
    unsigned short* fc2_wb  = wq + 524288;

    // 0. all weight conversions in one dispatch
    cvt_all<<<768, 256, 0, stream>>>(qkv_w, qkv_wb, proj_w, proj_wb,
                                     fc1_w, fc1_wb, fc2_w, fc2_wb);

    // 1. fused LN1 + shift/window-gather + QKV projection (x -> rB bf16)
    ln1_qkv<768><<<MROWS / 128, 256, 0, stream>>>(x, n1g, n1b, qkv_wb, qkv_b, rB);
    // 2. windowed attention (rB -> rB2 bf16)
    attn_kernel<<<(2048 / 4) * NH_, 256, 0, stream>>>(rB, rpb, rB2);
    // 3. proj + scatter + residual + fused LN2 (rB2 -> x1b bf16, rA bf16)
    proj_ln2<<<MROWS / 128, 256, 0, stream>>>(rB2, proj_wb, proj_b, x, n2g, n2b, x1b, rA);
    // 4. fused MLP (R19 swizzle): out = x1b + gelu(rA @ W1^T + b1) @ W2^T + b2
    mlp_fused<<<MROWS / 256, 512, 0, stream>>>(rA, fc1_wb, fc1_b, fc2_wb, fc2_b, x1b, out);
}